// Round 9
// baseline (263.930 us; speedup 1.0000x reference)
//
#include <hip/hip_runtime.h>
#include <hip/hip_fp16.h>
#include <math.h>

// GCN: h0 = lrelu(Agg(x@W0)+b0); h1 = lrelu(Agg(h0@W1)+b1); out = sigmoid(h1[idx]@Wm+bm)
// Agg (sym-norm + self loops): agg[d] = dinv[d] * ( sum_{e:dst=d} hs[src] + hs[d] ),
// hs = h * dinv[row], stored FP16.
// Layer-2 agg computed ONLY at the 20k selected nodes, fused with b1+lrelu+head+sigmoid.
// Gathers use 8-lane x uint4 (16B) streams: 8 lane-addresses per 128B edge row
// (address-throughput bound -> halves TA work vs 16x8B).
// CSR build: 256-partition binned scatter (write-combined) + per-bucket LDS counting sort.
// GEMM: fp16 MFMA 16x16x32, fp32 accum.

#define NPART 256
#define MAXB 2048  // max dst-buckets (N <= 131072)

typedef _Float16 h8 __attribute__((ext_vector_type(8)));
typedef float f4v __attribute__((ext_vector_type(4)));

__device__ __forceinline__ float lrelu(float x) { return x > 0.0f ? x : 0.01f * x; }

// ---------- partitioned binning (1024 threads, 4-edge ILP) ----------

__global__ __launch_bounds__(1024) void k_part_hist(const int* __restrict__ dst, int E,
                                                    int B, int* __restrict__ phist) {
    __shared__ int scnt[MAXB];
    int t = threadIdx.x, p = blockIdx.x;
    for (int i = t; i < B; i += 1024) scnt[i] = 0;
    __syncthreads();
    int ep = (((E + NPART - 1) / NPART) + 3) & ~3;
    int beg = p * ep, endi = min(E, beg + ep);
    int len = endi - beg; if (len < 0) len = 0;
    int cnt4 = len >> 2;
    for (int i = t; i < cnt4; i += 1024) {
        int4 d = *(const int4*)(dst + beg + i * 4);
        atomicAdd(&scnt[d.x >> 6], 1);
        atomicAdd(&scnt[d.y >> 6], 1);
        atomicAdd(&scnt[d.z >> 6], 1);
        atomicAdd(&scnt[d.w >> 6], 1);
    }
    int rem = len & 3;
    if (t < rem) atomicAdd(&scnt[dst[beg + cnt4 * 4 + t] >> 6], 1);
    __syncthreads();
    for (int i = t; i < B; i += 1024) phist[i * NPART + p] = scnt[i];
}

__global__ __launch_bounds__(1024) void k_part_scatter(const int* __restrict__ src,
                                                       const int* __restrict__ dst, int E,
                                                       int B, const int* __restrict__ pbase,
                                                       int* __restrict__ esA) {
    __shared__ int sbase[MAXB];
    int t = threadIdx.x, p = blockIdx.x;
    for (int i = t; i < B; i += 1024) sbase[i] = pbase[i * NPART + p];
    __syncthreads();
    int ep = (((E + NPART - 1) / NPART) + 3) & ~3;
    int beg = p * ep, endi = min(E, beg + ep);
    int len = endi - beg; if (len < 0) len = 0;
    int cnt4 = len >> 2;
    for (int i = t; i < cnt4; i += 1024) {
        int e = beg + i * 4;
        int4 d = *(const int4*)(dst + e);
        int4 s = *(const int4*)(src + e);
        int p0 = atomicAdd(&sbase[d.x >> 6], 1);
        int p1 = atomicAdd(&sbase[d.y >> 6], 1);
        int p2 = atomicAdd(&sbase[d.z >> 6], 1);
        int p3 = atomicAdd(&sbase[d.w >> 6], 1);
        esA[p0] = ((d.x & 63) << 24) | s.x;
        esA[p1] = ((d.y & 63) << 24) | s.y;
        esA[p2] = ((d.z & 63) << 24) | s.z;
        esA[p3] = ((d.w & 63) << 24) | s.w;
    }
    int rem = len & 3;
    if (t < rem) {
        int e = beg + cnt4 * 4 + t;
        int d = dst[e];
        int pos = atomicAdd(&sbase[d >> 6], 1);
        esA[pos] = ((d & 63) << 24) | src[e];
    }
}

// ---------- scan over BP = B*NPART ----------

__global__ void k_blocksum(const int* __restrict__ cnt, int N, int* __restrict__ bsum) {
    __shared__ int sm[256];
    int b = blockIdx.x, t = threadIdx.x;
    int base = b * 1024 + t * 4;
    int s = 0;
#pragma unroll
    for (int i = 0; i < 4; ++i) { int j = base + i; if (j < N) s += cnt[j]; }
    sm[t] = s; __syncthreads();
    for (int off = 128; off > 0; off >>= 1) {
        if (t < off) sm[t] += sm[t + off];
        __syncthreads();
    }
    if (t == 0) bsum[b] = sm[0];
}

__global__ void k_scan_bsum(int* __restrict__ bsum, int nb, int* __restrict__ offN) {
    __shared__ int sm[1024];
    int t = threadIdx.x;
    int v = (t < nb) ? bsum[t] : 0;
    sm[t] = v; __syncthreads();
    for (int d = 1; d < 1024; d <<= 1) {
        int add = (t >= d) ? sm[t - d] : 0;
        __syncthreads();
        sm[t] += add;
        __syncthreads();
    }
    if (t < nb) bsum[t] = sm[t] - v;       // exclusive
    if (t == nb - 1) *offN = sm[t];        // total == E
}

__global__ void k_scan_block(const int* __restrict__ cnt, const int* __restrict__ bsum,
                             int* __restrict__ off, int N) {
    __shared__ int sm[256];
    int b = blockIdx.x, t = threadIdx.x;
    int base = b * 1024 + t * 4;
    int v[4];
#pragma unroll
    for (int i = 0; i < 4; ++i) { int j = base + i; v[i] = (j < N) ? cnt[j] : 0; }
    int tsum = v[0] + v[1] + v[2] + v[3];
    sm[t] = tsum; __syncthreads();
    for (int d = 1; d < 256; d <<= 1) {
        int val = (t >= d) ? sm[t - d] : 0;
        __syncthreads();
        sm[t] += val;
        __syncthreads();
    }
    int run = sm[t] - tsum + bsum[b];
#pragma unroll
    for (int i = 0; i < 4; ++i) {
        int j = base + i;
        if (j < N) off[j] = run;
        run += v[i];
    }
}

// ---------- per-bucket counting sort -> node-ordered edges + off[] + dinv[] ----------

__global__ __launch_bounds__(256) void k_bsort(const int* __restrict__ pbase, int BP,
                                               const int* __restrict__ esA,
                                               int* __restrict__ esB,
                                               int* __restrict__ off,
                                               float* __restrict__ dinv,
                                               int N, int E) {
    __shared__ int hcnt[64];
    __shared__ int hoff[64];
    int t = threadIdx.x, b = blockIdx.x;
    int start = pbase[b * NPART];
    int endi  = pbase[min((b + 1) * NPART, BP)];
    int cnt = endi - start;

    if (t < 64) hcnt[t] = 0;
    __syncthreads();
    for (int i = t * 4; i < cnt; i += 1024) {
#pragma unroll
        for (int c = 0; c < 4; ++c)
            if (i + c < cnt) atomicAdd(&hcnt[(esA[start + i + c] >> 24) & 63], 1);
    }
    __syncthreads();

    if (t < 64) {  // wave 0: 64-wide scan -> exclusive offsets
        int c = hcnt[t];
        int v = c;
#pragma unroll
        for (int d = 1; d < 64; d <<= 1) {
            int u = __shfl_up(v, d);
            if (t >= d) v += u;
        }
        int pos = start + (v - c);
        hoff[t] = pos;
        int g = b * 64 + t;
        if (g < N) {
            off[g] = pos;
            dinv[g] = rsqrtf((float)c + 1.0f);  // +1 self loop
        }
        if (g == N - 1) off[N] = E;
    }
    __syncthreads();
    if (t < 64) hcnt[t] = hoff[t];  // cursors
    __syncthreads();

    for (int i = t * 4; i < cnt; i += 1024) {
#pragma unroll
        for (int c = 0; c < 4; ++c)
            if (i + c < cnt) {
                int v = esA[start + i + c];
                int pos = atomicAdd(&hcnt[(v >> 24) & 63], 1);
                esB[pos] = v & 0xFFFFFF;
            }
    }
}

// ---------- GEMM: fp16 MFMA 16x16x32, fp32 accumulate ----------

template <int K, typename AT>
__global__ __launch_bounds__(256) void k_gemm(const AT* __restrict__ A,
                                              const float* __restrict__ W,
                                              const float* __restrict__ dinv,
                                              __half* __restrict__ hout, int N) {
    constexpr int ASTR = K + 8;
    __shared__ _Float16 a16[64 * ASTR];
    __shared__ _Float16 wt16[64 * ASTR];
    int t = threadIdx.x, lane = t & 63, wv = t >> 6;
    int rowBase = blockIdx.x * 64;

#pragma unroll
    for (int i = 0; i < K / 16; ++i) {
        int g = i * 256 + t;
        int r = g / (K / 4), kq = g % (K / 4);
        int gr = rowBase + r; if (gr >= N) gr = N - 1;
        _Float16* p = a16 + r * ASTR + kq * 4;
        if constexpr (sizeof(AT) == 4) {
            float4 v = *(const float4*)((const float*)A + (size_t)gr * K + kq * 4);
            *(__half2*)(p)     = __floats2half2_rn(v.x, v.y);
            *(__half2*)(p + 2) = __floats2half2_rn(v.z, v.w);
        } else {
            *(uint2*)p = *(const uint2*)((const __half*)A + (size_t)gr * K + kq * 4);
        }
    }
#pragma unroll
    for (int i = 0; i < K / 16; ++i) {
        int g = i * 256 + t;
        int k = g >> 4, nq = g & 15;
        float4 v = *(const float4*)(W + (size_t)k * 64 + nq * 4);
        wt16[(nq * 4 + 0) * ASTR + k] = (_Float16)v.x;
        wt16[(nq * 4 + 1) * ASTR + k] = (_Float16)v.y;
        wt16[(nq * 4 + 2) * ASTR + k] = (_Float16)v.z;
        wt16[(nq * 4 + 3) * ASTR + k] = (_Float16)v.w;
    }
    __syncthreads();

    int m = lane & 15, q = lane >> 4;
    f4v acc[4] = {{0,0,0,0},{0,0,0,0},{0,0,0,0},{0,0,0,0}};
    const _Float16* arow = a16 + (wv * 16 + m) * ASTR + q * 8;
#pragma unroll
    for (int kt = 0; kt < K / 32; ++kt) {
        h8 af = *(const h8*)(arow + kt * 32);
#pragma unroll
        for (int nt = 0; nt < 4; ++nt) {
            h8 bf = *(const h8*)(wt16 + (nt * 16 + m) * ASTR + kt * 32 + q * 8);
            acc[nt] = __builtin_amdgcn_mfma_f32_16x16x32_f16(af, bf, acc[nt], 0, 0, 0);
        }
    }

    int r0 = rowBase + wv * 16 + q * 4;
#pragma unroll
    for (int reg = 0; reg < 4; ++reg) {
        int row = r0 + reg;
        if (row >= N) continue;
        float dv = dinv[row];
#pragma unroll
        for (int nt = 0; nt < 4; ++nt)
            hout[(size_t)row * 64 + nt * 16 + m] = (__half)(acc[nt][reg] * dv);
    }
}

// ---------- layer-1 aggregation: wave per node, 8 edge streams x uint4 ----------
// lane = (oct, l8): gather uint4 (8 halves) at hs[src*64 + l8*8]; 8 addrs per 128B row.

__global__ __launch_bounds__(256) void k_agg1(const int* __restrict__ off,
                                              const int* __restrict__ esB,
                                              const float* __restrict__ dinv,
                                              const __half* __restrict__ hs,
                                              const float* __restrict__ b0,
                                              __half* __restrict__ aout, int N) {
    int lane = threadIdx.x & 63;
    int node = (blockIdx.x * blockDim.x + threadIdx.x) >> 6;
    if (node >= N) return;
    int oct = lane >> 3, l8 = lane & 7;
    int beg = off[node], end = off[node + 1];

    float a[8] = {0, 0, 0, 0, 0, 0, 0, 0};
    auto ld = [&](int s) { return *(const uint4*)(hs + (size_t)s * 64 + l8 * 8); };
    auto acc8 = [&](uint4 u) {
        float2 f0 = __half22float2(*(__half2*)&u.x);
        float2 f1 = __half22float2(*(__half2*)&u.y);
        float2 f2 = __half22float2(*(__half2*)&u.z);
        float2 f3 = __half22float2(*(__half2*)&u.w);
        a[0] += f0.x; a[1] += f0.y; a[2] += f1.x; a[3] += f1.y;
        a[4] += f2.x; a[5] += f2.y; a[6] += f3.x; a[7] += f3.y;
    };
    if (oct == 0) acc8(ld(node));  // self loop
    int j = beg + oct;
    for (; j + 8 < end; j += 16) {
        int s0 = esB[j], s1 = esB[j + 8];
        uint4 u0 = ld(s0), u1 = ld(s1);
        acc8(u0); acc8(u1);
    }
    if (j < end) acc8(ld(esB[j]));

#pragma unroll
    for (int d = 8; d <= 32; d <<= 1) {
#pragma unroll
        for (int i = 0; i < 8; ++i) a[i] += __shfl_xor(a[i], d);
    }
    if (oct == 0) {
        float dv = dinv[node];
        float4 bl = *(const float4*)(b0 + l8 * 8);
        float4 bh = *(const float4*)(b0 + l8 * 8 + 4);
        uint4 u;
        *(__half2*)&u.x = __floats2half2_rn(lrelu(a[0] * dv + bl.x), lrelu(a[1] * dv + bl.y));
        *(__half2*)&u.y = __floats2half2_rn(lrelu(a[2] * dv + bl.z), lrelu(a[3] * dv + bl.w));
        *(__half2*)&u.z = __floats2half2_rn(lrelu(a[4] * dv + bh.x), lrelu(a[5] * dv + bh.y));
        *(__half2*)&u.w = __floats2half2_rn(lrelu(a[6] * dv + bh.z), lrelu(a[7] * dv + bh.w));
        *(uint4*)(aout + (size_t)node * 64 + l8 * 8) = u;
    }
}

// ---------- fused selected-node layer-2 agg + b1 + lrelu + head + sigmoid ----------

__global__ __launch_bounds__(256) void k_aggout(const int* __restrict__ idx,
                                                const int* __restrict__ off,
                                                const int* __restrict__ esB,
                                                const float* __restrict__ dinv,
                                                const __half* __restrict__ hs,
                                                const float* __restrict__ b1,
                                                const float* __restrict__ Wm,
                                                const float* __restrict__ bm,
                                                float* __restrict__ out, int NSEL) {
    int lane = threadIdx.x & 63;
    int wv = (blockIdx.x * blockDim.x + threadIdx.x) >> 6;
    if (wv >= NSEL) return;
    int node = idx[wv];
    int oct = lane >> 3, l8 = lane & 7;
    int beg = off[node], end = off[node + 1];

    float a[8] = {0, 0, 0, 0, 0, 0, 0, 0};
    auto ld = [&](int s) { return *(const uint4*)(hs + (size_t)s * 64 + l8 * 8); };
    auto acc8 = [&](uint4 u) {
        float2 f0 = __half22float2(*(__half2*)&u.x);
        float2 f1 = __half22float2(*(__half2*)&u.y);
        float2 f2 = __half22float2(*(__half2*)&u.z);
        float2 f3 = __half22float2(*(__half2*)&u.w);
        a[0] += f0.x; a[1] += f0.y; a[2] += f1.x; a[3] += f1.y;
        a[4] += f2.x; a[5] += f2.y; a[6] += f3.x; a[7] += f3.y;
    };
    if (oct == 0) acc8(ld(node));  // self loop
    int j = beg + oct;
    for (; j + 8 < end; j += 16) {
        int s0 = esB[j], s1 = esB[j + 8];
        uint4 u0 = ld(s0), u1 = ld(s1);
        acc8(u0); acc8(u1);
    }
    if (j < end) acc8(ld(esB[j]));

#pragma unroll
    for (int d = 8; d <= 32; d <<= 1) {  // all lanes end with full sums for their l8 slice
#pragma unroll
        for (int i = 0; i < 8; ++i) a[i] += __shfl_xor(a[i], d);
    }

    float dv = dinv[node];
    float4 bl = *(const float4*)(b1 + l8 * 8);
    float4 bh = *(const float4*)(b1 + l8 * 8 + 4);
    float hsel[8];
    hsel[0] = lrelu(a[0] * dv + bl.x); hsel[1] = lrelu(a[1] * dv + bl.y);
    hsel[2] = lrelu(a[2] * dv + bl.z); hsel[3] = lrelu(a[3] * dv + bl.w);
    hsel[4] = lrelu(a[4] * dv + bh.x); hsel[5] = lrelu(a[5] * dv + bh.y);
    hsel[6] = lrelu(a[6] * dv + bh.z); hsel[7] = lrelu(a[7] * dv + bh.w);
    if (oct == 0) {
        float4 o0 = {hsel[0], hsel[1], hsel[2], hsel[3]};
        float4 o1 = {hsel[4], hsel[5], hsel[6], hsel[7]};
        *(float4*)(out + (size_t)wv * 64 + l8 * 8) = o0;
        *(float4*)(out + (size_t)wv * 64 + l8 * 8 + 4) = o1;
    }

    // head: p[o] = sum_c hsel_c * Wm[c][o]; lane covers channels l8*8..l8*8+7
    const float* wr = Wm + (size_t)(8 * l8) * 5;
#pragma unroll
    for (int o = 0; o < 5; ++o) {
        float p = 0.0f;
#pragma unroll
        for (int i = 0; i < 8; ++i) p = fmaf(hsel[i], wr[i * 5 + o], p);
        p += __shfl_xor(p, 1); p += __shfl_xor(p, 2); p += __shfl_xor(p, 4);
        if (lane == 0)
            out[(size_t)NSEL * 64 + (size_t)wv * 5 + o] =
                1.0f / (1.0f + expf(-(p + bm[o])));
    }
}

extern "C" void kernel_launch(void* const* d_in, const int* in_sizes, int n_in,
                              void* d_out, int out_size, void* d_ws, size_t ws_size,
                              hipStream_t stream) {
    const float* x   = (const float*)d_in[0];
    const int*   ei  = (const int*)d_in[1];
    const int*   idx = (const int*)d_in[2];
    const float* W0  = (const float*)d_in[3];
    const float* b0  = (const float*)d_in[4];
    const float* W1  = (const float*)d_in[5];
    const float* b1  = (const float*)d_in[6];
    const float* Wm  = (const float*)d_in[7];
    const float* bm  = (const float*)d_in[8];

    int N    = in_sizes[0] / 128;
    int E    = in_sizes[1] / 2;
    int NSEL = in_sizes[2];
    const int* src = ei;
    const int* dst = ei + E;

    int B  = (N + 63) / 64;
    int BP = B * NPART;

    char* w = (char*)d_ws;
    size_t Na  = ((size_t)N + 1023) & ~(size_t)1023;
    size_t Ea  = ((size_t)E + 1023) & ~(size_t)1023;
    size_t BPa = ((size_t)BP + 1023) & ~(size_t)1023;
    float*  dinv  = (float*)w;                w += Na * 4;
    int*    phist = (int*)w;                  w += BPa * 4;
    int*    pbase = (int*)w;                  w += (BPa + 1024) * 4;
    int*    bsum  = (int*)w;                  w += 1024 * 4;
    int*    off   = (int*)w;                  w += (Na + 1024) * 4;
    int*    esA   = (int*)w;                  w += Ea * 4;
    int*    esB   = (int*)w;                  w += Ea * 4;
    __half* hs16  = (__half*)w;               w += (size_t)N * 64 * 2;  // h*dinv
    __half* a16g  = (__half*)w;                                        // lrelu(agg1+b0), fp16

    int nbp = (BP + 1023) / 1024;

    k_part_hist<<<NPART, 1024, 0, stream>>>(dst, E, B, phist);
    k_blocksum<<<nbp, 256, 0, stream>>>(phist, BP, bsum);
    k_scan_bsum<<<1, 1024, 0, stream>>>(bsum, nbp, pbase + BP);
    k_scan_block<<<nbp, 256, 0, stream>>>(phist, bsum, pbase, BP);
    k_part_scatter<<<NPART, 1024, 0, stream>>>(src, dst, E, B, pbase, esA);
    k_bsort<<<B, 256, 0, stream>>>(pbase, BP, esA, esB, off, dinv, N, E);

    int gemm_blocks = (N + 63) / 64;
    int agg_blocks  = (N + 3) / 4;

    k_gemm<128, float><<<gemm_blocks, 256, 0, stream>>>(x, W0, dinv, hs16, N);
    k_agg1<<<agg_blocks, 256, 0, stream>>>(off, esB, dinv, hs16, b0, a16g, N);
    k_gemm<64, __half><<<gemm_blocks, 256, 0, stream>>>(a16g, W1, dinv, hs16, N);
    k_aggout<<<(NSEL + 3) / 4, 256, 0, stream>>>(idx, off, esB, dinv, hs16, b1, Wm, bm,
                                                 (float*)d_out, NSEL);
}